// Round 10
// baseline (124.854 us; speedup 1.0000x reference)
//
#include <hip/hip_runtime.h>

#define DM 96
#define NH 4
#define DH 24
#define CAP 64            // per-node bucket capacity; deg ~ Poisson(16)
#define BSH 8             // 256 nodes per coarse bin
#define BCAP2 5120        // records per coarse bin; lambda ~4082, +16 sigma
#define ECHUNK 3072       // edges per scat block (12 per thread)
#define NODE_BLOCKS 2048  // persistent-wave grid for node_kernel

typedef __attribute__((ext_vector_type(8))) __bf16 bf16x8;
typedef __attribute__((ext_vector_type(4))) float f32x4;

__device__ inline unsigned short f2bf(float f) {            // RNE f32->bf16
    union { float f; unsigned int i; } c; c.f = f;
    unsigned int r = c.i + 0x7FFFu + ((c.i >> 16) & 1u);
    return (unsigned short)(r >> 16);
}
__device__ inline float lo_bf(unsigned int u) { union { unsigned int i; float f; } c; c.i = u << 16; return c.f; }
__device__ inline float hi_bf(unsigned int u) { union { unsigned int i; float f; } c; c.i = u & 0xFFFF0000u; return c.f; }

// ---------- scat: WT build + LDS counting-sort edge scatter into coarse bins ----------
__global__ __launch_bounds__(256) void scat_kernel(
    const float* __restrict__ qW, const float* __restrict__ kW, const float* __restrict__ vW,
    const int* __restrict__ rows, const int* __restrict__ cols,
    unsigned short* __restrict__ WT,
    int* __restrict__ gbcnt, uint2* __restrict__ bbuf, int e, int nbin)
{
    __shared__ int cnt0[256];
    __shared__ int excl[256];
    __shared__ int gbase[256];
    __shared__ uint2 stage[ECHUNK];   // 24 KB

    int t = threadIdx.x;

    // WT[mat][c][k] = bf16(W[k][c]) — spread across the grid, one elem per thread
    int gtid = blockIdx.x * 256 + t;
    if (gtid < 3 * DM * DM) {
        int mat = gtid / (DM * DM);
        int rr = gtid - mat * (DM * DM);
        int c = rr / DM, k = rr - c * DM;
        const float* W = (mat == 0) ? qW : (mat == 1) ? kW : vW;
        WT[gtid] = f2bf(W[k * DM + c]);
    }

    cnt0[t] = 0;
    __syncthreads();

    int base = blockIdx.x * ECHUNK;
    int r[12], c[12], lp[12];
    #pragma unroll
    for (int i = 0; i < 12; ++i) {
        int idx = base + i * 256 + t;          // coalesced
        bool ok = idx < e;
        r[i] = ok ? rows[idx] : -1;
        c[i] = ok ? cols[idx] : 0;
        if (ok) lp[i] = atomicAdd(&cnt0[r[i] >> BSH], 1);
    }
    __syncthreads();

    // Hillis-Steele inclusive scan of cnt0 into excl, then make exclusive
    excl[t] = cnt0[t];
    __syncthreads();
    for (int o = 1; o < 256; o <<= 1) {
        int x = (t >= o) ? excl[t - o] : 0;
        __syncthreads();
        excl[t] += x;
        __syncthreads();
    }
    int ex = excl[t] - cnt0[t];
    int total = excl[255];
    __syncthreads();
    excl[t] = ex;
    // one global atomic per non-empty bin
    if (t < nbin && cnt0[t] > 0) gbase[t] = atomicAdd(&gbcnt[t], cnt0[t]);
    __syncthreads();

    // stage records in bin-sorted order
    #pragma unroll
    for (int i = 0; i < 12; ++i) {
        if (r[i] >= 0) {
            int b = r[i] >> BSH;
            stage[excl[b] + lp[i]] = make_uint2((unsigned)r[i], (unsigned)c[i]);
        }
    }
    __syncthreads();

    // flush: consecutive j -> consecutive dest within each bin run => coalesced
    for (int j = t; j < total; j += 256) {
        uint2 rc = stage[j];
        int b = rc.x >> BSH;
        int pos = gbase[b] + (j - excl[b]);
        if (pos < BCAP2) bbuf[(size_t)b * BCAP2 + pos] = rc;
    }
}

// ---------- csr: per-bin re-scatter into per-node buckets (LDS counters) ----------
__global__ __launch_bounds__(256) void csr_kernel(
    const int* __restrict__ gbcnt, const uint2* __restrict__ bbuf,
    int* __restrict__ cnt, int* __restrict__ pcols, int n)
{
    __shared__ int lcnt[256];
    int b = blockIdx.x;
    int t = threadIdx.x;
    lcnt[t] = 0;
    __syncthreads();
    int m = gbcnt[b]; if (m > BCAP2) m = BCAP2;
    const uint2* src = bbuf + (size_t)b * BCAP2;
    int nbase = b << BSH;
    for (int i = t; i < m; i += 256) {
        uint2 rc = src[i];
        int pos = atomicAdd(&lcnt[(int)rc.x - nbase], 1);
        if (pos < CAP) pcols[(size_t)rc.x * CAP + pos] = (int)rc.y;
    }
    __syncthreads();
    int node = nbase + t;
    if (node < n) cnt[node] = lcnt[t];
}

// ---------- MFMA projection: Qf (f32), KVb (bf16, K|V interleaved); converts emb on the fly ----------
__global__ __launch_bounds__(256) void proj_mfma_kernel(
    const float* __restrict__ emb, const unsigned short* __restrict__ WT,
    float* __restrict__ Qf, unsigned short* __restrict__ KVb, int n)
{
    int l = threadIdx.x & 63;
    int w = threadIdx.x >> 6;
    int row0 = blockIdx.x * 64 + w * 16;
    int lr = l & 15;     // A row / B col / C col
    int lk = l >> 4;     // k-chunk 0..3
    int arow = row0 + lr; if (arow >= n) arow = n - 1;

    bf16x8 a[3];
    {
        const float4* e4p = (const float4*)(emb + (size_t)arow * DM);
        #pragma unroll
        for (int kb = 0; kb < 3; ++kb) {
            float4 f0 = e4p[kb * 8 + lk * 2];
            float4 f1 = e4p[kb * 8 + lk * 2 + 1];
            union { unsigned short u[8]; bf16x8 b; } cv;
            cv.u[0] = f2bf(f0.x); cv.u[1] = f2bf(f0.y); cv.u[2] = f2bf(f0.z); cv.u[3] = f2bf(f0.w);
            cv.u[4] = f2bf(f1.x); cv.u[5] = f2bf(f1.y); cv.u[6] = f2bf(f1.z); cv.u[7] = f2bf(f1.w);
            a[kb] = cv.b;
        }
    }

    for (int mat = 0; mat < 3; ++mat) {
        const unsigned short* Wm = WT + mat * DM * DM;
        f32x4 acc[6];
        #pragma unroll
        for (int tc = 0; tc < 6; ++tc) acc[tc] = (f32x4){0.f, 0.f, 0.f, 0.f};
        #pragma unroll
        for (int kb = 0; kb < 3; ++kb) {
            #pragma unroll
            for (int tc = 0; tc < 6; ++tc) {
                union { uint4 u; bf16x8 b; } bv;
                bv.u = *(const uint4*)&Wm[(size_t)(tc * 16 + lr) * DM + kb * 32 + lk * 8];
                acc[tc] = __builtin_amdgcn_mfma_f32_16x16x32_bf16(a[kb], bv.b, acc[tc], 0, 0, 0);
            }
        }
        #pragma unroll
        for (int tc = 0; tc < 6; ++tc) {
            #pragma unroll
            for (int r = 0; r < 4; ++r) {
                int grow = row0 + lk * 4 + r;    // C/D: row=(l>>4)*4+reg, col=l&15
                if (grow < n) {
                    if (mat == 0)
                        Qf[(size_t)grow * DM + tc * 16 + lr] = acc[tc][r];
                    else
                        KVb[(size_t)grow * (2 * DM) + (mat - 1) * DM + tc * 16 + lr] = f2bf(acc[tc][r]);
                }
            }
        }
    }
}

// ---------- fused attention: persistent waves, wave per node, 16-way split x 4 heads ----------
#define REDW(x) { x += __shfl_xor(x, 4); x += __shfl_xor(x, 8); x += __shfl_xor(x, 16); x += __shfl_xor(x, 32); }

__global__ __launch_bounds__(256) void node_kernel(
    const float* __restrict__ emb, const float* __restrict__ Qf,
    const unsigned short* __restrict__ KVb,
    const int* __restrict__ cnt, const int* __restrict__ pcols,
    float* __restrict__ out, int n)
{
    int w = threadIdx.x >> 6;
    int l = threadIdx.x & 63;
    int s = l >> 2;      // 0..15 edge split
    int h = l & 3;       // head
    int wid = blockIdx.x * 4 + w;
    int ws = gridDim.x * 4;

    int nextcnt = (wid < n) ? cnt[wid] : 0;

    for (int node = wid; node < n; node += ws) {
        int count = nextcnt;
        if (node + ws < n) nextcnt = cnt[node + ws];   // prefetch next node's count
        if (count > CAP) count = CAP;
        const int* bucket = pcols + (size_t)node * CAP;

        float q[24];
        {
            const f32x4* q4 = (const f32x4*)(Qf + (size_t)node * DM + h * DH);
            #pragma unroll
            for (int t = 0; t < 6; ++t) {
                f32x4 u = __builtin_nontemporal_load(q4 + t);
                q[t * 4 + 0] = u.x; q[t * 4 + 1] = u.y; q[t * 4 + 2] = u.z; q[t * 4 + 3] = u.w;
            }
        }
        float a[24];
        #pragma unroll
        for (int i = 0; i < 24; ++i) a[i] = 0.f;
        float denom = 0.f;

        for (int j = s; j < count; j += 16) {
            int c = bucket[j];
            const uint4* kp = (const uint4*)(KVb + (size_t)c * (2 * DM) + h * DH);
            uint4 ku[3] = {kp[0], kp[1], kp[2]};        // K slice
            uint4 vu[3] = {kp[12], kp[13], kp[14]};     // V slice (+96 shorts = +12 uint4)

            float dot = 0.f;
            #pragma unroll
            for (int t = 0; t < 3; ++t) {
                unsigned int uw[4] = {ku[t].x, ku[t].y, ku[t].z, ku[t].w};
                #pragma unroll
                for (int j2 = 0; j2 < 4; ++j2)
                    dot += lo_bf(uw[j2]) * q[t * 8 + j2 * 2] + hi_bf(uw[j2]) * q[t * 8 + j2 * 2 + 1];
            }
            dot = fminf(fmaxf(dot, -10.f), 10.f);
            float es = __expf(dot);
            denom += es;
            #pragma unroll
            for (int t = 0; t < 3; ++t) {
                unsigned int uw[4] = {vu[t].x, vu[t].y, vu[t].z, vu[t].w};
                #pragma unroll
                for (int j2 = 0; j2 < 4; ++j2) {
                    a[t * 8 + j2 * 2]     += es * lo_bf(uw[j2]);
                    a[t * 8 + j2 * 2 + 1] += es * hi_bf(uw[j2]);
                }
            }
        }

        REDW(denom)
        #pragma unroll
        for (int i = 0; i < 24; ++i) { REDW(a[i]) }

        if (s == 0) {
            float sc = 1.f / (denom + 1e-8f);
            const f32x4* e4 = (const f32x4*)(emb + (size_t)node * DM + h * DH);
            f32x4* o4 = (f32x4*)(out + (size_t)node * DM + h * DH);
            #pragma unroll
            for (int t = 0; t < 6; ++t) {
                f32x4 ev = __builtin_nontemporal_load(e4 + t);
                f32x4 ov;
                ov.x = ev.x + a[t * 4 + 0] * sc;
                ov.y = ev.y + a[t * 4 + 1] * sc;
                ov.z = ev.z + a[t * 4 + 2] * sc;
                ov.w = ev.w + a[t * 4 + 3] * sc;
                __builtin_nontemporal_store(ov, o4 + t);
            }
        }
    }
}

extern "C" void kernel_launch(void* const* d_in, const int* in_sizes, int n_in,
                              void* d_out, int out_size, void* d_ws, size_t ws_size,
                              hipStream_t stream) {
    const float* emb = (const float*)d_in[0];
    const float* qW  = (const float*)d_in[1];
    const float* kW  = (const float*)d_in[2];
    const float* vW  = (const float*)d_in[3];
    const int* rows  = (const int*)d_in[4];
    const int* cols  = (const int*)d_in[5];
    float* out = (float*)d_out;

    int n = in_sizes[0] / DM;     // 50000
    int e = in_sizes[4];          // 800000
    int nbin = (n + (1 << BSH) - 1) >> BSH;        // 196

    unsigned short* KVb = (unsigned short*)d_ws;         // n*192 bf16 (K|V interleaved)
    unsigned short* WT  = KVb + (size_t)n * 2 * DM;      // 3*96*96 bf16
    float* Qf = (float*)(WT + 3 * DM * DM);              // n*96 f32 — ALIASES bbuf
    uint2* bbuf = (uint2*)Qf;                            // nbin*BCAP2 uint2 (8 MB), dead before proj
    int* cnt   = (int*)(Qf + (size_t)n * DM);            // n
    int* gbcnt = cnt + n;                                // nbin
    int* pcols = gbcnt + nbin;                           // n*CAP

    hipMemsetAsync(gbcnt, 0, (size_t)nbin * sizeof(int), stream);

    int nscat = (e + ECHUNK - 1) / ECHUNK;               // 261
    scat_kernel<<<nscat, 256, 0, stream>>>(qW, kW, vW, rows, cols, WT, gbcnt, bbuf, e, nbin);

    csr_kernel<<<nbin, 256, 0, stream>>>(gbcnt, bbuf, cnt, pcols, n);

    proj_mfma_kernel<<<(n + 63) / 64, 256, 0, stream>>>(emb, WT, Qf, KVb, n);

    node_kernel<<<NODE_BLOCKS, 256, 0, stream>>>(emb, Qf, KVb, cnt, pcols, out, n);
}

// Round 13
// 104.099 us; speedup vs baseline: 1.1994x; 1.1994x over previous
//
#include <hip/hip_runtime.h>

#define DM 96
#define NH 4
#define DH 24
#define CAP 64            // per-node bucket capacity; deg ~ Poisson(16)
#define BSH 8             // 256 nodes per coarse bin
#define BCAP2 5120        // records per coarse bin; lambda ~4082, +16 sigma
#define ECHUNK 3072       // edges per scat block (12 per thread)

typedef __attribute__((ext_vector_type(8))) __bf16 bf16x8;
typedef __attribute__((ext_vector_type(4))) float f32x4;

__device__ inline unsigned short f2bf(float f) {            // RNE f32->bf16
    union { float f; unsigned int i; } c; c.f = f;
    unsigned int r = c.i + 0x7FFFu + ((c.i >> 16) & 1u);
    return (unsigned short)(r >> 16);
}
__device__ inline float lo_bf(unsigned int u) { union { unsigned int i; float f; } c; c.i = u << 16; return c.f; }
__device__ inline float hi_bf(unsigned int u) { union { unsigned int i; float f; } c; c.i = u & 0xFFFF0000u; return c.f; }

// ---------- scat: WT build + LDS counting-sort edge scatter into coarse bins ----------
__global__ __launch_bounds__(256) void scat_kernel(
    const float* __restrict__ qW, const float* __restrict__ kW, const float* __restrict__ vW,
    const int* __restrict__ rows, const int* __restrict__ cols,
    unsigned short* __restrict__ WT,
    int* __restrict__ gbcnt, uint2* __restrict__ bbuf, int e, int nbin)
{
    __shared__ int cnt0[256];
    __shared__ int excl[256];
    __shared__ int gbase[256];
    __shared__ uint2 stage[ECHUNK];   // 24 KB

    int t = threadIdx.x;

    int gtid = blockIdx.x * 256 + t;
    if (gtid < 3 * DM * DM) {
        int mat = gtid / (DM * DM);
        int rr = gtid - mat * (DM * DM);
        int c = rr / DM, k = rr - c * DM;
        const float* W = (mat == 0) ? qW : (mat == 1) ? kW : vW;
        WT[gtid] = f2bf(W[k * DM + c]);
    }

    cnt0[t] = 0;
    __syncthreads();

    int base = blockIdx.x * ECHUNK;
    int r[12], c[12], lp[12];
    #pragma unroll
    for (int i = 0; i < 12; ++i) {
        int idx = base + i * 256 + t;          // coalesced
        bool ok = idx < e;
        r[i] = ok ? rows[idx] : -1;
        c[i] = ok ? cols[idx] : 0;
        if (ok) lp[i] = atomicAdd(&cnt0[r[i] >> BSH], 1);
    }
    __syncthreads();

    excl[t] = cnt0[t];
    __syncthreads();
    for (int o = 1; o < 256; o <<= 1) {
        int x = (t >= o) ? excl[t - o] : 0;
        __syncthreads();
        excl[t] += x;
        __syncthreads();
    }
    int ex = excl[t] - cnt0[t];
    int total = excl[255];
    __syncthreads();
    excl[t] = ex;
    if (t < nbin && cnt0[t] > 0) gbase[t] = atomicAdd(&gbcnt[t], cnt0[t]);
    __syncthreads();

    #pragma unroll
    for (int i = 0; i < 12; ++i) {
        if (r[i] >= 0) {
            int b = r[i] >> BSH;
            stage[excl[b] + lp[i]] = make_uint2((unsigned)r[i], (unsigned)c[i]);
        }
    }
    __syncthreads();

    for (int j = t; j < total; j += 256) {
        uint2 rc = stage[j];
        int b = rc.x >> BSH;
        int pos = gbase[b] + (j - excl[b]);
        if (pos < BCAP2) bbuf[(size_t)b * BCAP2 + pos] = rc;
    }
}

// ---------- csr: per-bin re-scatter into per-node buckets (LDS counters) ----------
__global__ __launch_bounds__(256) void csr_kernel(
    const int* __restrict__ gbcnt, const uint2* __restrict__ bbuf,
    int* __restrict__ cnt, int* __restrict__ pcols, int n)
{
    __shared__ int lcnt[256];
    int b = blockIdx.x;
    int t = threadIdx.x;
    lcnt[t] = 0;
    __syncthreads();
    int m = gbcnt[b]; if (m > BCAP2) m = BCAP2;
    const uint2* src = bbuf + (size_t)b * BCAP2;
    int nbase = b << BSH;
    for (int i = t; i < m; i += 256) {
        uint2 rc = src[i];
        int pos = atomicAdd(&lcnt[(int)rc.x - nbase], 1);
        if (pos < CAP) pcols[(size_t)rc.x * CAP + pos] = (int)rc.y;
    }
    __syncthreads();
    int node = nbase + t;
    if (node < n) cnt[node] = lcnt[t];
}

// ---------- MFMA projection: Qf (f32), KVb (bf16, K|V interleaved); converts emb on the fly ----------
__global__ __launch_bounds__(256) void proj_mfma_kernel(
    const float* __restrict__ emb, const unsigned short* __restrict__ WT,
    float* __restrict__ Qf, unsigned short* __restrict__ KVb, int n)
{
    int l = threadIdx.x & 63;
    int w = threadIdx.x >> 6;
    int row0 = blockIdx.x * 64 + w * 16;
    int lr = l & 15;     // A row / B col / C col
    int lk = l >> 4;     // k-chunk 0..3
    int arow = row0 + lr; if (arow >= n) arow = n - 1;

    bf16x8 a[3];
    {
        const float4* e4p = (const float4*)(emb + (size_t)arow * DM);
        #pragma unroll
        for (int kb = 0; kb < 3; ++kb) {
            float4 f0 = e4p[kb * 8 + lk * 2];
            float4 f1 = e4p[kb * 8 + lk * 2 + 1];
            union { unsigned short u[8]; bf16x8 b; } cv;
            cv.u[0] = f2bf(f0.x); cv.u[1] = f2bf(f0.y); cv.u[2] = f2bf(f0.z); cv.u[3] = f2bf(f0.w);
            cv.u[4] = f2bf(f1.x); cv.u[5] = f2bf(f1.y); cv.u[6] = f2bf(f1.z); cv.u[7] = f2bf(f1.w);
            a[kb] = cv.b;
        }
    }

    for (int mat = 0; mat < 3; ++mat) {
        const unsigned short* Wm = WT + mat * DM * DM;
        f32x4 acc[6];
        #pragma unroll
        for (int tc = 0; tc < 6; ++tc) acc[tc] = (f32x4){0.f, 0.f, 0.f, 0.f};
        #pragma unroll
        for (int kb = 0; kb < 3; ++kb) {
            #pragma unroll
            for (int tc = 0; tc < 6; ++tc) {
                union { uint4 u; bf16x8 b; } bv;
                bv.u = *(const uint4*)&Wm[(size_t)(tc * 16 + lr) * DM + kb * 32 + lk * 8];
                acc[tc] = __builtin_amdgcn_mfma_f32_16x16x32_bf16(a[kb], bv.b, acc[tc], 0, 0, 0);
            }
        }
        #pragma unroll
        for (int tc = 0; tc < 6; ++tc) {
            #pragma unroll
            for (int r = 0; r < 4; ++r) {
                int grow = row0 + lk * 4 + r;    // C/D: row=(l>>4)*4+reg, col=l&15
                if (grow < n) {
                    if (mat == 0)
                        Qf[(size_t)grow * DM + tc * 16 + lr] = acc[tc][r];
                    else
                        KVb[(size_t)grow * (2 * DM) + (mat - 1) * DM + tc * 16 + lr] = f2bf(acc[tc][r]);
                }
            }
        }
    }
}

// ---------- fused attention: 4 nodes/wave, 4-way split x 4 heads, register buckets ----------
// lane l: nd = l>>4 (node within wave), s = (l>>2)&3 (edge split), h = l&3 (head)
// CRITICAL: every __shfl must execute with ALL 64 lanes in lockstep. The loop runs a
// wave-uniform iteration count nit = ceil(maxc/4); per-lane j = it*4+s; the entire
// memory/compute body is predicated on j < count. No divergent exit precedes a shfl.
#define RED2(x) { x += __shfl_xor(x, 4); x += __shfl_xor(x, 8); }

__global__ __launch_bounds__(256) void node_kernel(
    const float* __restrict__ emb, const float* __restrict__ Qf,
    const unsigned short* __restrict__ KVb,
    const int* __restrict__ cnt, const int* __restrict__ pcols,
    float* __restrict__ out, int n)
{
    int wv = (blockIdx.x * 256 + threadIdx.x) >> 6;   // global wave id
    int l = threadIdx.x & 63;
    int nd = l >> 4;
    int s  = (l >> 2) & 3;
    int h  = l & 3;
    int node = wv * 4 + nd;
    bool valid = node < n;
    int nodec = valid ? node : n - 1;

    int count = cnt[nodec];
    if (count > CAP) count = CAP;
    if (!valid) count = 0;

    // wave-uniform max count (count is uniform within each 16-lane nd group)
    int maxc = count;
    maxc = max(maxc, __shfl_xor(maxc, 16));
    maxc = max(maxc, __shfl_xor(maxc, 32));
    int nit = (maxc + 3) >> 2;           // wave-uniform iteration count

    // stage bucket slots 0..15: lane l holds slot (l&15) of node (wv*4 + l>>4)
    int bb = pcols[(size_t)nodec * CAP + (l & 15)];

    // Q: head h slice, f32, kept in registers
    float q[24];
    {
        const f32x4* q4 = (const f32x4*)(Qf + (size_t)nodec * DM + h * DH);
        #pragma unroll
        for (int t = 0; t < 6; ++t) {
            f32x4 u = q4[t];
            q[t * 4 + 0] = u.x; q[t * 4 + 1] = u.y; q[t * 4 + 2] = u.z; q[t * 4 + 3] = u.w;
        }
    }

    float a[24];
    #pragma unroll
    for (int i = 0; i < 24; ++i) a[i] = 0.f;
    float denom = 0.f;

    for (int it = 0; it < nit; ++it) {
        int j = it * 4 + s;
        // shfl executes unconditionally, all 64 lanes active — well-defined
        int c = __shfl(bb, (l & 48) + (j & 15));
        if (j >= 16 && j < count) c = pcols[(size_t)node * CAP + j];   // tail (deg > 16)

        if (j < count) {
            const uint4* kp = (const uint4*)(KVb + (size_t)c * (2 * DM) + h * DH);
            uint4 ku[3] = {kp[0], kp[1], kp[2]};        // K slice
            uint4 vu[3] = {kp[12], kp[13], kp[14]};     // V slice (+96 shorts = +12 uint4)

            float dot = 0.f;
            #pragma unroll
            for (int t = 0; t < 3; ++t) {
                unsigned int uw[4] = {ku[t].x, ku[t].y, ku[t].z, ku[t].w};
                #pragma unroll
                for (int j2 = 0; j2 < 4; ++j2)
                    dot += lo_bf(uw[j2]) * q[t * 8 + j2 * 2] + hi_bf(uw[j2]) * q[t * 8 + j2 * 2 + 1];
            }
            dot = fminf(fmaxf(dot, -10.f), 10.f);
            float es = __expf(dot);
            denom += es;
            #pragma unroll
            for (int t = 0; t < 3; ++t) {
                unsigned int uw[4] = {vu[t].x, vu[t].y, vu[t].z, vu[t].w};
                #pragma unroll
                for (int j2 = 0; j2 < 4; ++j2) {
                    a[t * 8 + j2 * 2]     += es * lo_bf(uw[j2]);
                    a[t * 8 + j2 * 2 + 1] += es * hi_bf(uw[j2]);
                }
            }
        }
    }

    // reduce over the 4 split lanes (bits 2-3); one instruction serves all 4 nodes
    RED2(denom)
    #pragma unroll
    for (int i = 0; i < 24; ++i) { RED2(a[i]) }

    if (s == 0 && valid) {
        float sc = 1.f / (denom + 1e-8f);
        const f32x4* e4 = (const f32x4*)(emb + (size_t)node * DM + h * DH);
        f32x4* o4 = (f32x4*)(out + (size_t)node * DM + h * DH);
        #pragma unroll
        for (int t = 0; t < 6; ++t) {
            f32x4 ev = e4[t];
            f32x4 ov;
            ov.x = ev.x + a[t * 4 + 0] * sc;
            ov.y = ev.y + a[t * 4 + 1] * sc;
            ov.z = ev.z + a[t * 4 + 2] * sc;
            ov.w = ev.w + a[t * 4 + 3] * sc;
            o4[t] = ov;
        }
    }
}

extern "C" void kernel_launch(void* const* d_in, const int* in_sizes, int n_in,
                              void* d_out, int out_size, void* d_ws, size_t ws_size,
                              hipStream_t stream) {
    const float* emb = (const float*)d_in[0];
    const float* qW  = (const float*)d_in[1];
    const float* kW  = (const float*)d_in[2];
    const float* vW  = (const float*)d_in[3];
    const int* rows  = (const int*)d_in[4];
    const int* cols  = (const int*)d_in[5];
    float* out = (float*)d_out;

    int n = in_sizes[0] / DM;     // 50000
    int e = in_sizes[4];          // 800000
    int nbin = (n + (1 << BSH) - 1) >> BSH;        // 196

    unsigned short* KVb = (unsigned short*)d_ws;         // n*192 bf16 (K|V interleaved)
    unsigned short* WT  = KVb + (size_t)n * 2 * DM;      // 3*96*96 bf16
    float* Qf = (float*)(WT + 3 * DM * DM);              // n*96 f32 — ALIASES bbuf
    uint2* bbuf = (uint2*)Qf;                            // nbin*BCAP2 uint2 (8 MB), dead before proj
    int* cnt   = (int*)(Qf + (size_t)n * DM);            // n
    int* gbcnt = cnt + n;                                // nbin
    int* pcols = gbcnt + nbin;                           // n*CAP

    hipMemsetAsync(gbcnt, 0, (size_t)nbin * sizeof(int), stream);

    int nscat = (e + ECHUNK - 1) / ECHUNK;               // 261
    scat_kernel<<<nscat, 256, 0, stream>>>(qW, kW, vW, rows, cols, WT, gbcnt, bbuf, e, nbin);

    csr_kernel<<<nbin, 256, 0, stream>>>(gbcnt, bbuf, cnt, pcols, n);

    proj_mfma_kernel<<<(n + 63) / 64, 256, 0, stream>>>(emb, WT, Qf, KVb, n);

    // 16 nodes per block (4 waves x 4 nodes)
    node_kernel<<<(n + 15) / 16, 256, 0, stream>>>(emb, Qf, KVb, cnt, pcols, out, n);
}

// Round 14
// 94.034 us; speedup vs baseline: 1.3278x; 1.1070x over previous
//
#include <hip/hip_runtime.h>

#define DM 96
#define NH 4
#define DH 24
#define CAP 64            // per-node bucket capacity; deg ~ Poisson(16)
#define BSH 8             // 256 nodes per coarse bin
#define BCAP2 5120        // records per coarse bin; lambda ~4082, +16 sigma
#define ECHUNK 3072       // edges per scat block (12 per thread)

typedef __attribute__((ext_vector_type(8))) __bf16 bf16x8;
typedef __attribute__((ext_vector_type(4))) float f32x4;

__device__ inline unsigned short f2bf(float f) {            // RNE f32->bf16
    union { float f; unsigned int i; } c; c.f = f;
    unsigned int r = c.i + 0x7FFFu + ((c.i >> 16) & 1u);
    return (unsigned short)(r >> 16);
}
__device__ inline float lo_bf(unsigned int u) { union { unsigned int i; float f; } c; c.i = u << 16; return c.f; }
__device__ inline float hi_bf(unsigned int u) { union { unsigned int i; float f; } c; c.i = u & 0xFFFF0000u; return c.f; }

// ---------- scat: WT build + LDS counting-sort edge scatter into coarse bins ----------
__global__ __launch_bounds__(256) void scat_kernel(
    const float* __restrict__ qW, const float* __restrict__ kW, const float* __restrict__ vW,
    const int* __restrict__ rows, const int* __restrict__ cols,
    unsigned short* __restrict__ WT,
    int* __restrict__ gbcnt, uint2* __restrict__ bbuf, int e, int nbin)
{
    __shared__ int cnt0[256];
    __shared__ int excl[256];
    __shared__ int gbase[256];
    __shared__ uint2 stage[ECHUNK];   // 24 KB

    int t = threadIdx.x;

    int gtid = blockIdx.x * 256 + t;
    if (gtid < 3 * DM * DM) {
        int mat = gtid / (DM * DM);
        int rr = gtid - mat * (DM * DM);
        int c = rr / DM, k = rr - c * DM;
        const float* W = (mat == 0) ? qW : (mat == 1) ? kW : vW;
        WT[gtid] = f2bf(W[k * DM + c]);
    }

    cnt0[t] = 0;
    __syncthreads();

    int base = blockIdx.x * ECHUNK;
    int r[12], c[12], lp[12];
    #pragma unroll
    for (int i = 0; i < 12; ++i) {
        int idx = base + i * 256 + t;          // coalesced
        bool ok = idx < e;
        r[i] = ok ? rows[idx] : -1;
        c[i] = ok ? cols[idx] : 0;
        if (ok) lp[i] = atomicAdd(&cnt0[r[i] >> BSH], 1);
    }
    __syncthreads();

    excl[t] = cnt0[t];
    __syncthreads();
    for (int o = 1; o < 256; o <<= 1) {
        int x = (t >= o) ? excl[t - o] : 0;
        __syncthreads();
        excl[t] += x;
        __syncthreads();
    }
    int ex = excl[t] - cnt0[t];
    int total = excl[255];
    __syncthreads();
    excl[t] = ex;
    if (t < nbin && cnt0[t] > 0) gbase[t] = atomicAdd(&gbcnt[t], cnt0[t]);
    __syncthreads();

    #pragma unroll
    for (int i = 0; i < 12; ++i) {
        if (r[i] >= 0) {
            int b = r[i] >> BSH;
            stage[excl[b] + lp[i]] = make_uint2((unsigned)r[i], (unsigned)c[i]);
        }
    }
    __syncthreads();

    for (int j = t; j < total; j += 256) {
        uint2 rc = stage[j];
        int b = rc.x >> BSH;
        int pos = gbase[b] + (j - excl[b]);
        if (pos < BCAP2) bbuf[(size_t)b * BCAP2 + pos] = rc;
    }
}

// ---------- merged: proj blocks [0, nproj) + csr blocks [nproj, nproj+nbin) ----------
__global__ __launch_bounds__(256) void csrproj_kernel(
    const float* __restrict__ emb, const unsigned short* __restrict__ WT,
    float* __restrict__ Qf, unsigned short* __restrict__ KVb,
    const int* __restrict__ gbcnt, const uint2* __restrict__ bbuf,
    int* __restrict__ cnt, int* __restrict__ pcols, int n, int nproj)
{
    if ((int)blockIdx.x < nproj) {
        // ---- projection: Qf (f32), KVb (bf16 K|V interleaved); emb->bf16 on the fly ----
        int l = threadIdx.x & 63;
        int w = threadIdx.x >> 6;
        int row0 = blockIdx.x * 64 + w * 16;
        int lr = l & 15;     // A row / B col / C col
        int lk = l >> 4;     // k-chunk 0..3
        int arow = row0 + lr; if (arow >= n) arow = n - 1;

        bf16x8 a[3];
        {
            const float4* e4p = (const float4*)(emb + (size_t)arow * DM);
            #pragma unroll
            for (int kb = 0; kb < 3; ++kb) {
                float4 f0 = e4p[kb * 8 + lk * 2];
                float4 f1 = e4p[kb * 8 + lk * 2 + 1];
                union { unsigned short u[8]; bf16x8 b; } cv;
                cv.u[0] = f2bf(f0.x); cv.u[1] = f2bf(f0.y); cv.u[2] = f2bf(f0.z); cv.u[3] = f2bf(f0.w);
                cv.u[4] = f2bf(f1.x); cv.u[5] = f2bf(f1.y); cv.u[6] = f2bf(f1.z); cv.u[7] = f2bf(f1.w);
                a[kb] = cv.b;
            }
        }

        for (int mat = 0; mat < 3; ++mat) {
            const unsigned short* Wm = WT + mat * DM * DM;
            f32x4 acc[6];
            #pragma unroll
            for (int tc = 0; tc < 6; ++tc) acc[tc] = (f32x4){0.f, 0.f, 0.f, 0.f};
            #pragma unroll
            for (int kb = 0; kb < 3; ++kb) {
                #pragma unroll
                for (int tc = 0; tc < 6; ++tc) {
                    union { uint4 u; bf16x8 b; } bv;
                    bv.u = *(const uint4*)&Wm[(size_t)(tc * 16 + lr) * DM + kb * 32 + lk * 8];
                    acc[tc] = __builtin_amdgcn_mfma_f32_16x16x32_bf16(a[kb], bv.b, acc[tc], 0, 0, 0);
                }
            }
            #pragma unroll
            for (int tc = 0; tc < 6; ++tc) {
                #pragma unroll
                for (int r = 0; r < 4; ++r) {
                    int grow = row0 + lk * 4 + r;    // C/D: row=(l>>4)*4+reg, col=l&15
                    if (grow < n) {
                        if (mat == 0)
                            Qf[(size_t)grow * DM + tc * 16 + lr] = acc[tc][r];
                        else
                            KVb[(size_t)grow * (2 * DM) + (mat - 1) * DM + tc * 16 + lr] = f2bf(acc[tc][r]);
                    }
                }
            }
        }
    } else {
        // ---- csr: per-bin re-scatter into per-node buckets (LDS counters) ----
        __shared__ int lcnt[256];
        int b = blockIdx.x - nproj;
        int t = threadIdx.x;
        lcnt[t] = 0;
        __syncthreads();
        int m = gbcnt[b]; if (m > BCAP2) m = BCAP2;
        const uint2* src = bbuf + (size_t)b * BCAP2;
        int nbase = b << BSH;
        for (int i = t; i < m; i += 256) {
            uint2 rc = src[i];
            int pos = atomicAdd(&lcnt[(int)rc.x - nbase], 1);
            if (pos < CAP) pcols[(size_t)rc.x * CAP + pos] = (int)rc.y;
        }
        __syncthreads();
        int node = nbase + t;
        if (node < n) cnt[node] = lcnt[t];
    }
}

// ---------- fused attention: 2 nodes/wave, 8-way split x 4 heads, register buckets ----------
// lane l: nd = l>>5, s = (l>>2)&7, h = l&3. All shfls run with 64 lanes in lockstep:
// wave-uniform nit; memory/compute body predicated on j < count.
#define RED3(x) { x += __shfl_xor(x, 4); x += __shfl_xor(x, 8); x += __shfl_xor(x, 16); }

__global__ __launch_bounds__(256) void node_kernel(
    const float* __restrict__ emb, const float* __restrict__ Qf,
    const unsigned short* __restrict__ KVb,
    const int* __restrict__ cnt, const int* __restrict__ pcols,
    float* __restrict__ out, int n)
{
    int wv = (blockIdx.x * 256 + threadIdx.x) >> 6;   // global wave id
    int l = threadIdx.x & 63;
    int nd = l >> 5;          // 0..1
    int s  = (l >> 2) & 7;    // 0..7
    int h  = l & 3;           // head
    int node = wv * 2 + nd;
    bool valid = node < n;
    int nodec = valid ? node : n - 1;

    int count = cnt[nodec];
    if (count > CAP) count = CAP;
    if (!valid) count = 0;

    int maxc = count;
    maxc = max(maxc, __shfl_xor(maxc, 32));
    int nit = (maxc + 7) >> 3;           // wave-uniform iteration count

    // register bucket: lane l holds slot (l&31) of its node — covers slots 0..31
    int bb = pcols[(size_t)nodec * CAP + (l & 31)];

    float q[24];
    {
        const f32x4* q4 = (const f32x4*)(Qf + (size_t)nodec * DM + h * DH);
        #pragma unroll
        for (int t = 0; t < 6; ++t) {
            f32x4 u = q4[t];
            q[t * 4 + 0] = u.x; q[t * 4 + 1] = u.y; q[t * 4 + 2] = u.z; q[t * 4 + 3] = u.w;
        }
    }

    float a[24];
    #pragma unroll
    for (int i = 0; i < 24; ++i) a[i] = 0.f;
    float denom = 0.f;

    for (int it = 0; it < nit; ++it) {
        int j = it * 8 + s;
        int c = __shfl(bb, (l & 32) + (j & 31));                        // lockstep shfl
        if (j >= 32 && j < count) c = pcols[(size_t)node * CAP + j];    // tail (deg > 32), rare

        if (j < count) {
            const uint4* kp = (const uint4*)(KVb + (size_t)c * (2 * DM) + h * DH);
            uint4 ku[3] = {kp[0], kp[1], kp[2]};        // K slice
            uint4 vu[3] = {kp[12], kp[13], kp[14]};     // V slice (+96 shorts = +12 uint4)

            float dot = 0.f;
            #pragma unroll
            for (int t = 0; t < 3; ++t) {
                unsigned int uw[4] = {ku[t].x, ku[t].y, ku[t].z, ku[t].w};
                #pragma unroll
                for (int j2 = 0; j2 < 4; ++j2)
                    dot += lo_bf(uw[j2]) * q[t * 8 + j2 * 2] + hi_bf(uw[j2]) * q[t * 8 + j2 * 2 + 1];
            }
            dot = fminf(fmaxf(dot, -10.f), 10.f);
            float es = __expf(dot);
            denom += es;
            #pragma unroll
            for (int t = 0; t < 3; ++t) {
                unsigned int uw[4] = {vu[t].x, vu[t].y, vu[t].z, vu[t].w};
                #pragma unroll
                for (int j2 = 0; j2 < 4; ++j2) {
                    a[t * 8 + j2 * 2]     += es * lo_bf(uw[j2]);
                    a[t * 8 + j2 * 2 + 1] += es * hi_bf(uw[j2]);
                }
            }
        }
    }

    RED3(denom)
    #pragma unroll
    for (int i = 0; i < 24; ++i) { RED3(a[i]) }

    if (s == 0 && valid) {
        float sc = 1.f / (denom + 1e-8f);
        const f32x4* e4 = (const f32x4*)(emb + (size_t)node * DM + h * DH);
        f32x4* o4 = (f32x4*)(out + (size_t)node * DM + h * DH);
        #pragma unroll
        for (int t = 0; t < 6; ++t) {
            f32x4 ev = e4[t];
            f32x4 ov;
            ov.x = ev.x + a[t * 4 + 0] * sc;
            ov.y = ev.y + a[t * 4 + 1] * sc;
            ov.z = ev.z + a[t * 4 + 2] * sc;
            ov.w = ev.w + a[t * 4 + 3] * sc;
            o4[t] = ov;
        }
    }
}

extern "C" void kernel_launch(void* const* d_in, const int* in_sizes, int n_in,
                              void* d_out, int out_size, void* d_ws, size_t ws_size,
                              hipStream_t stream) {
    const float* emb = (const float*)d_in[0];
    const float* qW  = (const float*)d_in[1];
    const float* kW  = (const float*)d_in[2];
    const float* vW  = (const float*)d_in[3];
    const int* rows  = (const int*)d_in[4];
    const int* cols  = (const int*)d_in[5];
    float* out = (float*)d_out;

    int n = in_sizes[0] / DM;     // 50000
    int e = in_sizes[4];          // 800000
    int nbin = (n + (1 << BSH) - 1) >> BSH;        // 196

    // NO aliasing: csr (reads bbuf) and proj (writes Qf) run concurrently in one kernel.
    unsigned short* KVb = (unsigned short*)d_ws;         // n*192 bf16  (19.2 MB)
    unsigned short* WT  = KVb + (size_t)n * 2 * DM;      // 3*96*96 bf16 (55 KB)
    float* Qf = (float*)(WT + 3 * DM * DM);              // n*96 f32    (19.2 MB)
    int* cnt   = (int*)(Qf + (size_t)n * DM);            // n           (0.2 MB)
    int* gbcnt = cnt + n;                                // nbin
    int* pcols = gbcnt + nbin;                           // n*CAP       (12.8 MB)
    uint2* bbuf = (uint2*)(pcols + (size_t)n * CAP);     // nbin*BCAP2  (8.0 MB)

    hipMemsetAsync(gbcnt, 0, (size_t)nbin * sizeof(int), stream);

    int nscat = (e + ECHUNK - 1) / ECHUNK;               // 261
    scat_kernel<<<nscat, 256, 0, stream>>>(qW, kW, vW, rows, cols, WT, gbcnt, bbuf, e, nbin);

    int nproj = (n + 63) / 64;                           // 782
    csrproj_kernel<<<nproj + nbin, 256, 0, stream>>>(emb, WT, Qf, KVb,
                                                     gbcnt, bbuf, cnt, pcols, n, nproj);

    node_kernel<<<(n + 7) / 8, 256, 0, stream>>>(emb, Qf, KVb, cnt, pcols, out, n);
}